// Round 1
// baseline (541.352 us; speedup 1.0000x reference)
//
#include <hip/hip_runtime.h>

#define S_DIM 4096
#define E_DIM 1024
#define H_DIM 8

typedef __bf16 bf16x8 __attribute__((ext_vector_type(8)));
typedef float  f32x4  __attribute__((ext_vector_type(4)));

// Async global->LDS, 16B per lane. LDS dest is wave-uniform base + lane*16.
__device__ __forceinline__ void async16(const __bf16* gsrc, __bf16* lbase, int lane)
{
#if __has_builtin(__builtin_amdgcn_global_load_lds)
    __builtin_amdgcn_global_load_lds(
        (const __attribute__((address_space(1))) unsigned int*)gsrc,
        (__attribute__((address_space(3))) unsigned int*)lbase, 16, 0, 0);
#else
    ((int4*)lbase)[lane] = *(const int4*)gsrc;
#endif
}

// ---------------------------------------------------------------------------
// Operand staging into LDS (bf16 sources only) for gemm128.
// MODE 0: NT [mn,k] k-contig -> async global_load_lds, tile stride 64 (no pad)
// MODE 2: TN [k,mn] k-major  -> transpose via packed b64, static XOR swizzle,
//         tile stride 72. True col c lives at LDS row (c&~7)|((c&7)^((c>>3)&7)).
// ---------------------------------------------------------------------------
template <int MODE>
__device__ __forceinline__ void stage_op(const __bf16* __restrict__ src, int ld,
                                         int mn0, int k0, __bf16* lds, int tid)
{
    if constexpr (MODE == 0) {
        const int w = tid >> 6, l = tid & 63;
        const int r8 = l >> 3, c8 = (l & 7) << 3;
#pragma unroll
        for (int i = 0; i < 4; i++) {
            const int rbase = w * 32 + i * 8;
            const __bf16* g = src + (size_t)(mn0 + rbase + r8) * ld + k0 + c8;
            async16(g, &lds[rbase * 64], l);
        }
    } else {
        // cols mn0 + (tid&15)*8 .. +8 ; krows k0 + (tid>>4)*4 .. +4
        const int cg = tid & 15, kg = tid >> 4;
        __bf16 h[4][8];
#pragma unroll
        for (int r = 0; r < 4; r++) {
            const __bf16* s = src + (size_t)(k0 + kg * 4 + r) * ld + mn0 + cg * 8;
            *(int4*)&h[r][0] = *(const int4*)s;
        }
        const int xr = cg & 7;
#pragma unroll
        for (int j = 0; j < 8; j++) {            // j static -> h[][] in VGPRs
            union { __bf16 q[4]; unsigned long long v; } u;
            u.q[0]=h[0][j]; u.q[1]=h[1][j]; u.q[2]=h[2][j]; u.q[3]=h[3][j];
            const int scol = cg * 8 + (j ^ xr);  // swizzle in address only
            *(unsigned long long*)&lds[scol * 72 + kg * 4] = u.v;
        }
    }
}

// ---------------------------------------------------------------------------
// 128x128-tile bf16 MFMA GEMM (kept for TN-staged operands: G, Mcat).
// OUT: 0=bf16 store, 1=fp32 store, 2=fp32 atomicAdd (split-K; bias ignored).
// ---------------------------------------------------------------------------
template <int AM, int BM, int OUT>
__global__ __launch_bounds__(256) void gemm128(
    const __bf16* __restrict__ Ag, const __bf16* __restrict__ Bg,
    void* __restrict__ Cg, const float* __restrict__ biasg,
    int Klen, int kPerZ, int lda, int ldb, int ldc,
    long long sA, long long sB, long long sC, float scale)
{
    __shared__ __bf16 As[128 * 72];
    __shared__ __bf16 Bs[128 * 72];
    constexpr int SA = (AM == 2) ? 72 : 64;
    constexpr int SB = (BM == 2) ? 72 : 64;

    const int tid  = threadIdx.x;
    const int lane = tid & 63;
    const int wave = tid >> 6;
    const int t    = lane & 15;
    const int quad = lane >> 4;
    const int wm   = wave >> 1;
    const int wn   = wave & 1;
    const int m0   = blockIdx.y * 128;
    const int n0   = blockIdx.x * 128;
    const size_t zi = blockIdx.z;

    const __bf16* A = (kPerZ == 0) ? Ag + zi * sA : Ag;
    const __bf16* B = (kPerZ == 0) ? Bg + zi * sB : Bg;
    const int kbeg = kPerZ ? (int)zi * kPerZ : 0;

    int rowA[4], rowB[4];
#pragma unroll
    for (int i = 0; i < 4; i++) {
        int ra = wm * 64 + i * 16 + t;
        int rb = wn * 64 + i * 16 + t;
        rowA[i] = (AM == 2) ? (ra ^ ((ra >> 3) & 7)) : ra;
        rowB[i] = (BM == 2) ? (rb ^ ((rb >> 3) & 7)) : rb;
    }

    f32x4 acc[4][4];
#pragma unroll
    for (int i = 0; i < 4; i++)
#pragma unroll
        for (int j = 0; j < 4; j++) { f32x4 z = {0.f,0.f,0.f,0.f}; acc[i][j] = z; }

    for (int k0 = kbeg; k0 < kbeg + Klen; k0 += 64) {
        stage_op<AM>(A, lda, m0, k0, As, tid);
        stage_op<BM>(B, ldb, n0, k0, Bs, tid);
        __syncthreads();
#pragma unroll
        for (int kk = 0; kk < 2; kk++) {
            bf16x8 af[4], bfv[4];
#pragma unroll
            for (int i = 0; i < 4; i++)
                af[i] = *(const bf16x8*)(&As[rowA[i] * SA + kk*32 + quad*8]);
#pragma unroll
            for (int j = 0; j < 4; j++)
                bfv[j] = *(const bf16x8*)(&Bs[rowB[j] * SB + kk*32 + quad*8]);
#pragma unroll
            for (int i = 0; i < 4; i++)
#pragma unroll
                for (int j = 0; j < 4; j++)
                    acc[i][j] = __builtin_amdgcn_mfma_f32_16x16x32_bf16(af[i], bfv[j], acc[i][j], 0, 0, 0);
        }
        __syncthreads();
    }

#pragma unroll
    for (int i = 0; i < 4; i++) {
        const int rowb = m0 + wm*64 + i*16 + quad*4;
#pragma unroll
        for (int j = 0; j < 4; j++) {
            const int col = n0 + wn*64 + j*16 + t;
            const float bv = biasg ? biasg[col] : 0.f;
#pragma unroll
            for (int r = 0; r < 4; r++) {
                const float v = acc[i][j][r] * scale + bv;
                if constexpr (OUT == 0) {
                    __bf16* C = (__bf16*)Cg + zi * sC;
                    C[(size_t)(rowb + r) * ldc + col] = (__bf16)v;
                } else if constexpr (OUT == 1) {
                    float* C = (float*)Cg + zi * sC;
                    C[(size_t)(rowb + r) * ldc + col] = v;
                } else {
                    float* C = (float*)Cg;
                    atomicAdd(&C[(size_t)(rowb + r) * ldc + col], v);
                }
            }
        }
    }
}

// ---------------------------------------------------------------------------
// 256x256-tile bf16 MFMA GEMM, NT-NT only: C[m,n] = sum_k A[m,k]*B[n,k].
// 512 threads = 8 waves (2M x 4N), wave tile 128x64, BK=32.
// 4-ring LDS (4 x (A 16KB + B 16KB) = 128 KiB), global_load_lds staged 3
// K-tiles ahead with counted s_waitcnt vmcnt (never 0 mid-loop), ONE raw
// s_barrier per K-tile, setprio(1) around each 16-MFMA half-phase.
// LDS XOR swizzle: slot of row r holds logical 16B-group (slot ^ sx(r)),
// sx(r) = (r ^ (r>>2)) & 3 -> fragment ds_read_b128 is <=2-way (free).
// Source pre-swizzle: lane fetches global group (lane&3)^(lane>>2)^(lane>>4).
// Ring safety: tile kt+3 (ring (kt-1)&3) is issued only AFTER barrier kt,
// which proves every wave finished reading that ring during iter kt-1.
// vmcnt: 4 loads/wave/tile in flight for tiles kt+1,kt+2 -> vmcnt(8) proves
// tile kt fully landed (then barrier makes it proven for all waves).
// B head-select for block-diagonal batched B: B += (m0>>10)*sB.
// OUT: 0=bf16 store, 1=fp32 store at Cg+zi*sC, 2=fp32 atomicAdd.
// ---------------------------------------------------------------------------
template <int OUT>
__global__ __launch_bounds__(512, 2) void gemm256(
    const __bf16* __restrict__ Ag, const __bf16* __restrict__ Bg,
    void* __restrict__ Cg, int Klen, int kPerZ,
    int lda, int ldb, int ldc, long long sB, long long sC)
{
    __shared__ __bf16 sm[4 * 2 * 256 * 32];   // ring r: A @ r*16384, B @ +8192

    const int tid  = threadIdx.x;
    const int lane = tid & 63;
    const int wave = tid >> 6;
    const int wm = wave >> 2, wn = wave & 3;
    const int t = lane & 15, q = lane >> 4;
    const int m0 = blockIdx.y * 256;
    const int n0 = blockIdx.x * 256;
    const int zi = blockIdx.z;
    const int kbeg = zi * kPerZ;
    const int NT = Klen >> 5;                  // K-tiles of 32

    // staging addresses: chunk = one operand K-tile (256x32), 2 loads/thread.
    // load R covers rows R*128 + wave*16 + (lane>>2), 16B group (lane&3),
    // fetched from pre-swizzled global group cg.
    const int cg = ((lane & 3) ^ (lane >> 2) ^ (lane >> 4)) & 3;
    const __bf16* gA = Ag + (size_t)(m0 + wave*16 + (lane>>2)) * lda + kbeg + cg*8;
    const __bf16* gB = Bg + (size_t)(m0 >> 10) * sB
                          + (size_t)(n0 + wave*16 + (lane>>2)) * ldb + kbeg + cg*8;

    auto stageA = [&](int kt) {
        __bf16* l = &sm[(kt & 3) * 16384 + wave * 512];
        const __bf16* g = gA + (size_t)kt * 32;
        async16(g, l, lane);
        async16(g + (size_t)128 * lda, l + 4096, lane);
    };
    auto stageB = [&](int kt) {
        __bf16* l = &sm[(kt & 3) * 16384 + 8192 + wave * 512];
        const __bf16* g = gB + (size_t)kt * 32;
        async16(g, l, lane);
        async16(g + (size_t)128 * ldb, l + 4096, lane);
    };

    // fragment read offsets (elements). row = frag_row_base + t, swizzled
    // 8-elem slot so = (q ^ sx(row))*8 with sx(row) = (t ^ (t>>2)) & 3.
    const int so = ((q ^ t ^ (t >> 2)) & 3) * 8;
    const int arow = (wm * 128 + t) * 32 + so;
    const int brow = (wn * 64  + t) * 32 + so;

    f32x4 acc[8][4];
#pragma unroll
    for (int i = 0; i < 8; i++)
#pragma unroll
        for (int j = 0; j < 4; j++) { f32x4 z = {0.f,0.f,0.f,0.f}; acc[i][j] = z; }

    // prologue: stage tiles 0,1,2 (12 loads/wave outstanding)
#pragma unroll
    for (int p = 0; p < 3; p++)
        if (p < NT) { stageA(p); stageB(p); }

    for (int kt = 0; kt < NT; ++kt) {
        const int rem = NT - 1 - kt;           // tiles staged beyond kt: min(rem,2)
        if (rem >= 2)      asm volatile("s_waitcnt vmcnt(8)" ::: "memory");
        else if (rem == 1) asm volatile("s_waitcnt vmcnt(4)" ::: "memory");
        else               asm volatile("s_waitcnt vmcnt(0)" ::: "memory");
        __builtin_amdgcn_s_barrier();
        asm volatile("" ::: "memory");         // keep LDS reads below barrier

        const __bf16* ra = &sm[(kt & 3) * 16384];
        const __bf16* rb = ra + 8192;

        bf16x8 bfr[4];
#pragma unroll
        for (int j = 0; j < 4; j++) bfr[j] = *(const bf16x8*)&rb[brow + j * 512];
        bf16x8 afr[4];
#pragma unroll
        for (int i = 0; i < 4; i++) afr[i] = *(const bf16x8*)&ra[arow + i * 512];
        if (kt + 3 < NT) stageA(kt + 3);

        __builtin_amdgcn_s_setprio(1);
#pragma unroll
        for (int i = 0; i < 4; i++)
#pragma unroll
            for (int j = 0; j < 4; j++)
                acc[i][j] = __builtin_amdgcn_mfma_f32_16x16x32_bf16(afr[i], bfr[j], acc[i][j], 0, 0, 0);
        __builtin_amdgcn_s_setprio(0);

#pragma unroll
        for (int i = 0; i < 4; i++) afr[i] = *(const bf16x8*)&ra[arow + (i + 4) * 512];
        if (kt + 3 < NT) stageB(kt + 3);

        __builtin_amdgcn_s_setprio(1);
#pragma unroll
        for (int i = 0; i < 4; i++)
#pragma unroll
            for (int j = 0; j < 4; j++)
                acc[i + 4][j] = __builtin_amdgcn_mfma_f32_16x16x32_bf16(afr[i], bfr[j], acc[i + 4][j], 0, 0, 0);
        __builtin_amdgcn_s_setprio(0);
    }

#pragma unroll
    for (int i = 0; i < 8; i++) {
        const int rowb = m0 + wm * 128 + i * 16 + q * 4;
#pragma unroll
        for (int j = 0; j < 4; j++) {
            const int col = n0 + wn * 64 + j * 16 + t;
#pragma unroll
            for (int r = 0; r < 4; r++) {
                const float v = acc[i][j][r];
                if constexpr (OUT == 0) {
                    ((__bf16*)Cg)[(size_t)(rowb + r) * ldc + col] = (__bf16)v;
                } else if constexpr (OUT == 1) {
                    float* C = (float*)Cg + (size_t)zi * sC;
                    C[(size_t)(rowb + r) * ldc + col] = v;
                } else {
                    atomicAdd(&((float*)Cg)[(size_t)(rowb + r) * ldc + col], v);
                }
            }
        }
    }
}

// fp32 -> bf16, 8 elems/thread, exact-size grid (n multiple of 2048).
__global__ __launch_bounds__(256) void cvt_bf16(
    const float* __restrict__ in, __bf16* __restrict__ out)
{
    const size_t i = ((size_t)blockIdx.x * 256 + threadIdx.x) * 8;
    float4 a = *(const float4*)(in + i);
    float4 b = *(const float4*)(in + i + 4);
    union { __bf16 h[8]; int4 v; } u;
    u.h[0]=(__bf16)a.x; u.h[1]=(__bf16)a.y; u.h[2]=(__bf16)a.z; u.h[3]=(__bf16)a.w;
    u.h[4]=(__bf16)b.x; u.h[5]=(__bf16)b.y; u.h[6]=(__bf16)b.z; u.h[7]=(__bf16)b.w;
    *(int4*)(out + i) = u.v;
}

// u[e] = sum_s x[s][e].  64 blocks x 64 rows; u pre-zeroed.
__global__ __launch_bounds__(256) void colsum_u(const float* __restrict__ x, float* __restrict__ u)
{
    const int c = threadIdx.x * 4;
    float4 a = {0.f,0.f,0.f,0.f};
    const int r0 = blockIdx.x * 64;
    for (int r = 0; r < 64; r++) {
        float4 v = *(const float4*)(x + (size_t)(r0 + r) * E_DIM + c);
        a.x += v.x; a.y += v.y; a.z += v.z; a.w += v.w;
    }
    atomicAdd(&u[c+0], a.x); atomicAdd(&u[c+1], a.y);
    atomicAdd(&u[c+2], a.z); atomicAdd(&u[c+3], a.w);
}

// kq[r] = Wk[r,:]·u ; qq[r] = Wq[r,:]·u  (r = h*E+j, 8192 rows each)
__global__ __launch_bounds__(256) void gemv_u(
    const float* __restrict__ Wk, const float* __restrict__ Wq,
    const float* __restrict__ u, float* __restrict__ kq, float* __restrict__ qq)
{
    const int gw = blockIdx.x * 4 + (threadIdx.x >> 6);
    const int lane = threadIdx.x & 63;
    const float* W = (gw < 8192) ? Wk + (size_t)gw * E_DIM
                                 : Wq + (size_t)(gw - 8192) * E_DIM;
    float s = 0.f;
#pragma unroll
    for (int i = 0; i < 4; i++) {
        float4 w = *(const float4*)(W + lane*16 + i*4);
        float4 z = *(const float4*)(u + lane*16 + i*4);
        s += w.x*z.x + w.y*z.y + w.z*z.z + w.w*z.w;
    }
#pragma unroll
    for (int o = 32; o > 0; o >>= 1) s += __shfl_down(s, o);
    if (lane == 0) { if (gw < 8192) kq[gw] = s; else qq[gw - 8192] = s; }
}

// zb[h*E+f] = sum_o bv[h][o] * A[h][o][f]; zb pre-zeroed. grid (4,8,4)
__global__ __launch_bounds__(256) void colsum_zb(
    const __bf16* __restrict__ Ab, const float* __restrict__ bv, float* __restrict__ zb)
{
    const int h = blockIdx.y;
    const int f = blockIdx.x * 256 + threadIdx.x;
    const int o0 = blockIdx.z * 256;
    const __bf16* A = Ab + (size_t)h * E_DIM * E_DIM + (size_t)o0 * E_DIM + f;
    const float* bvh = bv + h * E_DIM + o0;
    float s = 0.f;
    for (int o = 0; o < 256; o++) s += bvh[o] * (float)A[(size_t)o * E_DIM];
    atomicAdd(&zb[h * E_DIM + f], s);
}

// oc[g] = zb·Wz[g,:] + bz[g]   (K=8192, one wave per row)
__global__ __launch_bounds__(256) void gemv_oc(
    const float* __restrict__ Wz, const float* __restrict__ zb,
    const float* __restrict__ bz, float* __restrict__ oc)
{
    const int gw = blockIdx.x * 4 + (threadIdx.x >> 6);
    const int lane = threadIdx.x & 63;
    const float* W = Wz + (size_t)gw * (H_DIM * E_DIM);
    float s = 0.f;
#pragma unroll
    for (int i = 0; i < 32; i++) {
        float4 w = *(const float4*)(W + i*256 + lane*4);
        float4 z = *(const float4*)(zb + i*256 + lane*4);
        s += w.x*z.x + w.y*z.y + w.z*z.z + w.w*z.w;
    }
#pragma unroll
    for (int o = 32; o > 0; o >>= 1) s += __shfl_down(s, o);
    if (lane == 0) oc[gw] = s + bz[gw];
}

// softmax over f with fused rank-1 bias terms and 1/sqrt(E) scale.
__global__ __launch_bounds__(256) void softmax_fused(
    const float* __restrict__ Sc, const float* __restrict__ kq,
    const float* __restrict__ qq, const float* __restrict__ bk,
    const float* __restrict__ bq, __bf16* __restrict__ Aout)
{
    __shared__ float red[4];
    const int row = blockIdx.x;
    const int h = row >> 10;
    const int tid = threadIdx.x, lane = tid & 63, wave = tid >> 6;
    const float kqj = kq[row], bkj = bk[row];
    const float cst = (float)S_DIM * bkj;

    float4 v = ((const float4*)(Sc + (size_t)row * E_DIM))[tid];
    const int c = tid * 4;
    float4 qv = *(const float4*)(qq + (h << 10) + c);
    float4 bv = *(const float4*)(bq + (h << 10) + c);
    v.x = (v.x + kqj*bv.x + bkj*qv.x + cst*bv.x) * 0.03125f;
    v.y = (v.y + kqj*bv.y + bkj*qv.y + cst*bv.y) * 0.03125f;
    v.z = (v.z + kqj*bv.z + bkj*qv.z + cst*bv.z) * 0.03125f;
    v.w = (v.w + kqj*bv.w + bkj*qv.w + cst*bv.w) * 0.03125f;

    float m = fmaxf(fmaxf(v.x, v.y), fmaxf(v.z, v.w));
#pragma unroll
    for (int o = 32; o > 0; o >>= 1) m = fmaxf(m, __shfl_down(m, o));
    if (lane == 0) red[wave] = m;
    __syncthreads();
    m = fmaxf(fmaxf(red[0], red[1]), fmaxf(red[2], red[3]));
    __syncthreads();

    const float e0 = __expf(v.x - m), e1 = __expf(v.y - m);
    const float e2 = __expf(v.z - m), e3 = __expf(v.w - m);
    float s = e0 + e1 + e2 + e3;
#pragma unroll
    for (int o = 32; o > 0; o >>= 1) s += __shfl_down(s, o);
    if (lane == 0) red[wave] = s;
    __syncthreads();
    s = red[0] + red[1] + red[2] + red[3];
    const float inv = 1.f / s;

    __bf16* out = Aout + (size_t)row * E_DIM + c;
    out[0] = (__bf16)(e0*inv); out[1] = (__bf16)(e1*inv);
    out[2] = (__bf16)(e2*inv); out[3] = (__bf16)(e3*inv);
}

// LN + residual. X = sum of NPART fp32 partials (stride S*E) + optional
// per-column bias cb. out = LN(X)*g + b + resid.
template <int NPART, bool CB, bool WRITE_BF16>
__global__ __launch_bounds__(256) void ln_residual(
    const float* __restrict__ X, const float* __restrict__ cb,
    const float* __restrict__ resid,
    const float* __restrict__ g, const float* __restrict__ b,
    __bf16* __restrict__ outB, float* __restrict__ outF)
{
    __shared__ float redS[4], redQ[4];
    const int row = blockIdx.x;
    const int tid = threadIdx.x, lane = tid & 63, wave = tid >> 6;
    const size_t SE = (size_t)S_DIM * E_DIM;

    float4 v = ((const float4*)(X + (size_t)row * E_DIM))[tid];
#pragma unroll
    for (int p = 1; p < NPART; ++p) {
        float4 v1 = ((const float4*)(X + (size_t)p * SE + (size_t)row * E_DIM))[tid];
        v.x += v1.x; v.y += v1.y; v.z += v1.z; v.w += v1.w;
    }
    if constexpr (CB) {
        float4 cv = ((const float4*)cb)[tid];
        v.x += cv.x; v.y += cv.y; v.z += cv.z; v.w += cv.w;
    }
    float s = v.x + v.y + v.z + v.w;
    float q = v.x*v.x + v.y*v.y + v.z*v.z + v.w*v.w;
#pragma unroll
    for (int o = 32; o > 0; o >>= 1) { s += __shfl_down(s, o); q += __shfl_down(q, o); }
    if (lane == 0) { redS[wave] = s; redQ[wave] = q; }
    __syncthreads();
    s = redS[0]+redS[1]+redS[2]+redS[3];
    q = redQ[0]+redQ[1]+redQ[2]+redQ[3];

    const float mean = s * (1.f / E_DIM);
    const float var  = q * (1.f / E_DIM) - mean * mean;
    const float rstd = rsqrtf(var + 1e-5f);

    const int c0 = tid * 4;
    float4 rv = ((const float4*)(resid + (size_t)row * E_DIM))[tid];
    const float res[4] = {rv.x, rv.y, rv.z, rv.w};
    const float* vp = &v.x;
#pragma unroll
    for (int i = 0; i < 4; i++) {
        const float o = (vp[i] - mean) * rstd * g[c0+i] + b[c0+i] + res[i];
        outF[(size_t)row * E_DIM + c0 + i] = o;
        if constexpr (WRITE_BF16) outB[(size_t)row * E_DIM + c0 + i] = (__bf16)o;
    }
}

// ---------------------------------------------------------------------------
extern "C" void kernel_launch(void* const* d_in, const int* in_sizes, int n_in,
                              void* d_out, int out_size, void* d_ws, size_t ws_size,
                              hipStream_t stream)
{
    const float* x   = (const float*)d_in[0];
    const float* Wq  = (const float*)d_in[1];
    const float* bq  = (const float*)d_in[2];
    const float* Wk  = (const float*)d_in[3];
    const float* bk  = (const float*)d_in[4];
    const float* Wv  = (const float*)d_in[5];
    const float* bv  = (const float*)d_in[6];
    const float* Wz  = (const float*)d_in[7];
    const float* bz  = (const float*)d_in[8];
    const float* g1  = (const float*)d_in[9];
    const float* b1  = (const float*)d_in[10];
    const float* Wf  = (const float*)d_in[11];
    const float* bfp = (const float*)d_in[12];
    const float* g2  = (const float*)d_in[13];
    const float* b2  = (const float*)d_in[14];

    char* ws = (char*)d_ws;
    const long long EE = (long long)E_DIM * E_DIM;
    const long long SE = (long long)S_DIM * E_DIM;
    const size_t MB = 1024ull * 1024ull;

    // bf16 operand copies
    __bf16* xb   = (__bf16*)(ws);             //  8 MiB
    __bf16* Wqb  = (__bf16*)(ws +   8*MB);    // 16 MiB
    __bf16* Wkb  = (__bf16*)(ws +  24*MB);    // 16 MiB
    __bf16* Wvb  = (__bf16*)(ws +  40*MB);    // 16 MiB
    __bf16* Wzb  = (__bf16*)(ws +  56*MB);    // 16 MiB
    __bf16* Wfb  = (__bf16*)(ws +  72*MB);    //  2 MiB
    float*  Gf   = (float*) (ws +  74*MB);    //  4 MiB
    __bf16* Gb   = (__bf16*)(ws +  78*MB);    //  2 MiB
    float*  PTf  = (float*) (ws +  80*MB);    //  4 MiB
    __bf16* PTb  = (__bf16*)(ws +  84*MB);    //  2 MiB
    float*  u    = (float*) (ws +  86*MB);
    float*  kq   = (float*) (ws +  86*MB +  65536);
    float*  qq   = (float*) (ws +  86*MB + 131072);
    float*  zb   = (float*) (ws +  86*MB + 196608);
    float*  oc   = (float*) (ws +  86*MB + 262144);
    __bf16* LN1b = (__bf16*)(ws +  87*MB);    //  8 MiB
    float*  LN1f = (float*) (ws +  95*MB);    // 16 MiB
    __bf16* Tb   = (__bf16*)(ws + 111*MB);    // 16 MiB  (dead after scores)
    float*  Sc   = (float*) (ws + 127*MB);    // 32 MiB  (dead after softmax)
    __bf16* Ab   = (__bf16*)(ws + 159*MB);    // 16 MiB  (dead after Mcat/zb)
    __bf16* Mcat = (__bf16*)(ws + 175*MB);    // 16 MiB  (dead after PT; end 191)
    float*  Ob   = (float*) (ws + 111*MB);    // 64 MiB  4 partials (over Tb+Sc+Ab)
    float*  FNb  = (float*) (ws + 111*MB);    // 64 MiB  4 partials (Ob dead after LN1)

    dim3 blk(256);
    dim3 blk2(512);

    // zero accumulators (ws is 0xAA-poisoned)
    hipMemsetAsync(Gf,  0, 4*MB, stream);
    hipMemsetAsync(PTf, 0, 4*MB, stream);
    hipMemsetAsync(u,   0, E_DIM*4, stream);
    hipMemsetAsync(zb,  0, H_DIM*E_DIM*4, stream);

    // fp32 -> bf16 operand conversions
    cvt_bf16<<<dim3(2048), blk, 0, stream>>>(x,  xb);
    cvt_bf16<<<dim3(4096), blk, 0, stream>>>(Wq, Wqb);
    cvt_bf16<<<dim3(4096), blk, 0, stream>>>(Wk, Wkb);
    cvt_bf16<<<dim3(4096), blk, 0, stream>>>(Wv, Wvb);
    cvt_bf16<<<dim3(4096), blk, 0, stream>>>(Wz, Wzb);
    cvt_bf16<<<dim3(512),  blk, 0, stream>>>(Wf, Wfb);

    // u = colsum(x); kq = Wk u; qq = Wq u  (fp32 exact)
    colsum_u<<<dim3(64), blk, 0, stream>>>(x, u);
    gemv_u<<<dim3(4096), blk, 0, stream>>>(Wk, Wq, u, kq, qq);

    // G = x^T x  (TN both, split-K 8x512, atomic fp32) ; then bf16 copy
    gemm128<2, 2, 2><<<dim3(8, 8, 8), blk, 0, stream>>>(
        xb, xb, (void*)Gf, nullptr, 512, 512, E_DIM, E_DIM, E_DIM, 0, 0, 0, 1.f);
    cvt_bf16<<<dim3(512), blk, 0, stream>>>(Gf, Gb);

    // T = Wk_all G  (flat M=8192, shared B; G symmetric) -> bf16
    gemm256<0><<<dim3(4, 32, 1), blk2, 0, stream>>>(
        Wkb, Gb, (void*)Tb, E_DIM, 0, E_DIM, E_DIM, E_DIM, 0, 0);
    // scores_raw = T Wq_h^T  (flat M=8192, per-head B via m0>>10) -> fp32
    gemm256<1><<<dim3(4, 32, 1), blk2, 0, stream>>>(
        Tb, Wqb, (void*)Sc, E_DIM, 0, E_DIM, E_DIM, E_DIM, EE, 0);
    // A_h = softmax((raw + rank1)/32)
    softmax_fused<<<dim3(H_DIM * E_DIM), blk, 0, stream>>>(Sc, kq, qq, bk, bq, Ab);

    // Mcat[e][h*E+f] = (Wv_h^T A_h)[e][f]  (TN both)
    gemm128<2, 2, 0><<<dim3(8, 8, 8), blk, 0, stream>>>(
        Wvb, Ab, (void*)Mcat, nullptr, E_DIM, 0, E_DIM, E_DIM, H_DIM * E_DIM,
        EE, EE, E_DIM, 1.f);
    // zb = bv^T A ; oc = Wz zb + bz
    colsum_zb<<<dim3(4, 8, 4), blk, 0, stream>>>(Ab, bv, zb);
    gemv_oc<<<dim3(256), blk, 0, stream>>>(Wz, zb, bz, oc);

    // PT[g][e] = sum_F Wz[g][F] Mcat[e][F]  (split-K 8x1024, atomic fp32)
    gemm256<2><<<dim3(4, 4, 8), blk2, 0, stream>>>(
        Wzb, Mcat, (void*)PTf, 1024, 1024, H_DIM * E_DIM, H_DIM * E_DIM,
        E_DIM, 0, 0);
    cvt_bf16<<<dim3(512), blk, 0, stream>>>(PTf, PTb);

    // O partials = x PT^T  (split-K 4x256 -> 4 fp32 partials; bias oc in LN)
    gemm256<1><<<dim3(4, 16, 4), blk2, 0, stream>>>(
        xb, PTb, (void*)Ob, 256, 256, E_DIM, E_DIM, E_DIM, 0, SE);
    // LN1 = LN(O0+O1+O2+O3+oc)*g1+b1 + x
    ln_residual<4, true, true><<<dim3(S_DIM), blk, 0, stream>>>(
        Ob, oc, x, g1, b1, LN1b, LN1f);

    // FN partials = LN1 Wf^T  (split-K 4x256; bias bf in LN)
    gemm256<1><<<dim3(4, 16, 4), blk2, 0, stream>>>(
        LN1b, Wfb, (void*)FNb, 256, 256, E_DIM, E_DIM, E_DIM, 0, SE);
    // out = LN(FN0..FN3+bf)*g2+b2 + LN1
    ln_residual<4, true, false><<<dim3(S_DIM), blk, 0, stream>>>(
        FNb, bfp, LN1f, g2, b2, nullptr, (float*)d_out);
}

// Round 2
// 523.578 us; speedup vs baseline: 1.0339x; 1.0339x over previous
//
#include <hip/hip_runtime.h>

#define S_DIM 4096
#define E_DIM 1024
#define H_DIM 8

typedef __bf16 bf16x8 __attribute__((ext_vector_type(8)));
typedef float  f32x4  __attribute__((ext_vector_type(4)));

// Async global->LDS, 16B per lane. LDS dest is wave-uniform base + lane*16.
__device__ __forceinline__ void async16(const __bf16* gsrc, __bf16* lbase, int lane)
{
#if __has_builtin(__builtin_amdgcn_global_load_lds)
    __builtin_amdgcn_global_load_lds(
        (const __attribute__((address_space(1))) unsigned int*)gsrc,
        (__attribute__((address_space(3))) unsigned int*)lbase, 16, 0, 0);
#else
    ((int4*)lbase)[lane] = *(const int4*)gsrc;
#endif
}

// ---------------------------------------------------------------------------
// Operand staging into LDS (bf16 sources only) for gemm128.
// MODE 0: NT [mn,k] k-contig -> async global_load_lds, tile stride 64 (no pad)
// MODE 2: TN [k,mn] k-major  -> transpose via packed b64, static XOR swizzle,
//         tile stride 72. True col c lives at LDS row (c&~7)|((c&7)^((c>>3)&7)).
// ---------------------------------------------------------------------------
template <int MODE>
__device__ __forceinline__ void stage_op(const __bf16* __restrict__ src, int ld,
                                         int mn0, int k0, __bf16* lds, int tid)
{
    if constexpr (MODE == 0) {
        const int w = tid >> 6, l = tid & 63;
        const int r8 = l >> 3, c8 = (l & 7) << 3;
#pragma unroll
        for (int i = 0; i < 4; i++) {
            const int rbase = w * 32 + i * 8;
            const __bf16* g = src + (size_t)(mn0 + rbase + r8) * ld + k0 + c8;
            async16(g, &lds[rbase * 64], l);
        }
    } else {
        // cols mn0 + (tid&15)*8 .. +8 ; krows k0 + (tid>>4)*4 .. +4
        const int cg = tid & 15, kg = tid >> 4;
        __bf16 h[4][8];
#pragma unroll
        for (int r = 0; r < 4; r++) {
            const __bf16* s = src + (size_t)(k0 + kg * 4 + r) * ld + mn0 + cg * 8;
            *(int4*)&h[r][0] = *(const int4*)s;
        }
        const int xr = cg & 7;
#pragma unroll
        for (int j = 0; j < 8; j++) {            // j static -> h[][] in VGPRs
            union { __bf16 q[4]; unsigned long long v; } u;
            u.q[0]=h[0][j]; u.q[1]=h[1][j]; u.q[2]=h[2][j]; u.q[3]=h[3][j];
            const int scol = cg * 8 + (j ^ xr);  // swizzle in address only
            *(unsigned long long*)&lds[scol * 72 + kg * 4] = u.v;
        }
    }
}

// ---------------------------------------------------------------------------
// 128x128-tile bf16 MFMA GEMM (kept for TN-staged operands: G, Mcat).
// OUT: 0=bf16 store, 1=fp32 store, 2=fp32 atomicAdd (split-K; bias ignored).
// ---------------------------------------------------------------------------
template <int AM, int BM, int OUT>
__global__ __launch_bounds__(256) void gemm128(
    const __bf16* __restrict__ Ag, const __bf16* __restrict__ Bg,
    void* __restrict__ Cg, const float* __restrict__ biasg,
    int Klen, int kPerZ, int lda, int ldb, int ldc,
    long long sA, long long sB, long long sC, float scale)
{
    __shared__ __bf16 As[128 * 72];
    __shared__ __bf16 Bs[128 * 72];
    constexpr int SA = (AM == 2) ? 72 : 64;
    constexpr int SB = (BM == 2) ? 72 : 64;

    const int tid  = threadIdx.x;
    const int lane = tid & 63;
    const int wave = tid >> 6;
    const int t    = lane & 15;
    const int quad = lane >> 4;
    const int wm   = wave >> 1;
    const int wn   = wave & 1;
    const int m0   = blockIdx.y * 128;
    const int n0   = blockIdx.x * 128;
    const size_t zi = blockIdx.z;

    const __bf16* A = (kPerZ == 0) ? Ag + zi * sA : Ag;
    const __bf16* B = (kPerZ == 0) ? Bg + zi * sB : Bg;
    const int kbeg = kPerZ ? (int)zi * kPerZ : 0;

    int rowA[4], rowB[4];
#pragma unroll
    for (int i = 0; i < 4; i++) {
        int ra = wm * 64 + i * 16 + t;
        int rb = wn * 64 + i * 16 + t;
        rowA[i] = (AM == 2) ? (ra ^ ((ra >> 3) & 7)) : ra;
        rowB[i] = (BM == 2) ? (rb ^ ((rb >> 3) & 7)) : rb;
    }

    f32x4 acc[4][4];
#pragma unroll
    for (int i = 0; i < 4; i++)
#pragma unroll
        for (int j = 0; j < 4; j++) { f32x4 z = {0.f,0.f,0.f,0.f}; acc[i][j] = z; }

    for (int k0 = kbeg; k0 < kbeg + Klen; k0 += 64) {
        stage_op<AM>(A, lda, m0, k0, As, tid);
        stage_op<BM>(B, ldb, n0, k0, Bs, tid);
        __syncthreads();
#pragma unroll
        for (int kk = 0; kk < 2; kk++) {
            bf16x8 af[4], bfv[4];
#pragma unroll
            for (int i = 0; i < 4; i++)
                af[i] = *(const bf16x8*)(&As[rowA[i] * SA + kk*32 + quad*8]);
#pragma unroll
            for (int j = 0; j < 4; j++)
                bfv[j] = *(const bf16x8*)(&Bs[rowB[j] * SB + kk*32 + quad*8]);
#pragma unroll
            for (int i = 0; i < 4; i++)
#pragma unroll
                for (int j = 0; j < 4; j++)
                    acc[i][j] = __builtin_amdgcn_mfma_f32_16x16x32_bf16(af[i], bfv[j], acc[i][j], 0, 0, 0);
        }
        __syncthreads();
    }

#pragma unroll
    for (int i = 0; i < 4; i++) {
        const int rowb = m0 + wm*64 + i*16 + quad*4;
#pragma unroll
        for (int j = 0; j < 4; j++) {
            const int col = n0 + wn*64 + j*16 + t;
            const float bv = biasg ? biasg[col] : 0.f;
#pragma unroll
            for (int r = 0; r < 4; r++) {
                const float v = acc[i][j][r] * scale + bv;
                if constexpr (OUT == 0) {
                    __bf16* C = (__bf16*)Cg + zi * sC;
                    C[(size_t)(rowb + r) * ldc + col] = (__bf16)v;
                } else if constexpr (OUT == 1) {
                    float* C = (float*)Cg + zi * sC;
                    C[(size_t)(rowb + r) * ldc + col] = v;
                } else {
                    float* C = (float*)Cg;
                    atomicAdd(&C[(size_t)(rowb + r) * ldc + col], v);
                }
            }
        }
    }
}

// ---------------------------------------------------------------------------
// 256x128-tile bf16 MFMA GEMM, NT-NT only: C[m,n] = sum_k A[m,k]*B[n,k].
// 512 threads = 8 waves (4M x 2N), wave tile 64x64, BK=32.
// LDS: A ring 4x(256x32)=64KB + B ring 4x(128x32)=32KB = 96 KiB.
// m201-shaped phase per K-tile:
//   { 8 ds_read_b128 (ring kt) ; stage ring kt+3 (3 global_load_lds) ;
//     counted vmcnt ; s_barrier ; lgkmcnt(0)+sched_barrier ;
//     setprio(1) 16 MFMA setprio(0) ; s_barrier }
// so ds_read latency spans the barrier and hides under other waves' MFMAs.
// vmcnt proof schedule (3 loads/ring/wave): after staging kt+3, outstanding =
// rings kt+1..kt+3 (9 loads); vmcnt(6) proves ring kt+1 for next iter's
// reads (tail: rem==2 -> 3, rem==1 -> 0). Prologue stages rings 0..2 then
// vmcnt(6)+barrier proves ring 0. Requires NT >= 3.
// Ring overwrite safe: each wave's lgkmcnt(0) drains its ring-(kt-1) reads
// before the end barrier that gates stage(kt+3) (same slot) issue.
// LDS XOR swizzle (unchanged from verified R1): slot s of row r holds global
// 16B-group s ^ f(r), f(r) = (r&3)^((r>>2)&3); staged via pre-swizzled global
// source group, read back with the same XOR -> ds_read_b128 conflict-light.
// B head-select for block-diagonal batched B: B += (m0>>10)*sB.
// OUT: 0=bf16 store, 1=fp32 store at Cg+zi*sC, 2=fp32 atomicAdd.
// ---------------------------------------------------------------------------
template <int OUT>
__global__ __launch_bounds__(512, 2) void gemm256(
    const __bf16* __restrict__ Ag, const __bf16* __restrict__ Bg,
    void* __restrict__ Cg, int Klen, int kPerZ,
    int lda, int ldb, int ldc, long long sB, long long sC)
{
    __shared__ __bf16 smA[4 * 256 * 32];   // 64 KB
    __shared__ __bf16 smB[4 * 128 * 32];   // 32 KB

    const int tid  = threadIdx.x;
    const int lane = tid & 63;
    const int wave = tid >> 6;
    const int wm = wave >> 1, wn = wave & 1;   // 4M x 2N, wave tile 64x64
    const int t = lane & 15, q = lane >> 4;
    const int m0 = blockIdx.y * 256;
    const int n0 = blockIdx.x * 128;
    const int zi = blockIdx.z;
    const int kbeg = zi * kPerZ;
    const int NT = Klen >> 5;                  // K-tiles of 32 (NT >= 3)

    // staging: A tile 256x32 = 2 loads/wave, B tile 128x32 = 1 load/wave.
    // lane covers row chunkbase + (lane>>2), 16B slot (lane&3), fetched from
    // pre-swizzled global group cg so LDS slot s holds group s ^ f(row).
    const int cg = ((lane & 3) ^ (lane >> 2) ^ (lane >> 4)) & 3;
    const __bf16* gA = Ag + (size_t)(m0 + wave*16 + (lane>>2)) * lda + kbeg + cg*8;
    const __bf16* gB = Bg + (size_t)(m0 >> 10) * sB
                          + (size_t)(n0 + wave*16 + (lane>>2)) * ldb + kbeg + cg*8;

    auto stageA = [&](int kt) {
        __bf16* l = &smA[(kt & 3) * 8192 + wave * 512];
        const __bf16* g = gA + (size_t)kt * 32;
        async16(g, l, lane);
        async16(g + (size_t)128 * lda, l + 4096, lane);
    };
    auto stageB = [&](int kt) {
        __bf16* l = &smB[(kt & 3) * 4096 + wave * 512];
        async16(gB + (size_t)kt * 32, l, lane);
    };

    // fragment read offsets (elements): row = base + t, 8-elem slot
    // (q ^ f(t))*8 since base % 16 == 0 -> f(row) = f(t).
    const int so = ((q ^ t ^ (t >> 2)) & 3) * 8;
    const int arow = (wm * 64 + t) * 32 + so;
    const int brow = (wn * 64 + t) * 32 + so;

    f32x4 acc[4][4];
#pragma unroll
    for (int i = 0; i < 4; i++)
#pragma unroll
        for (int j = 0; j < 4; j++) { f32x4 z = {0.f,0.f,0.f,0.f}; acc[i][j] = z; }

    // prologue: stage rings 0,1,2 (9 loads/wave); prove ring 0.
#pragma unroll
    for (int p = 0; p < 3; p++)
        if (p < NT) { stageA(p); stageB(p); }
    asm volatile("s_waitcnt vmcnt(6)" ::: "memory");
    __builtin_amdgcn_s_barrier();
    asm volatile("" ::: "memory");

    for (int kt = 0; kt < NT; ++kt) {
        const __bf16* ra = &smA[(kt & 3) * 8192];
        const __bf16* rb = &smB[(kt & 3) * 4096];

        bf16x8 afr[4], bfr[4];
#pragma unroll
        for (int i = 0; i < 4; i++) afr[i] = *(const bf16x8*)&ra[arow + i * 512];
#pragma unroll
        for (int j = 0; j < 4; j++) bfr[j] = *(const bf16x8*)&rb[brow + j * 512];

        if (kt + 3 < NT) { stageA(kt + 3); stageB(kt + 3); }

        const int rem = NT - 1 - kt;           // rings still needed beyond kt
        if (rem >= 3)      asm volatile("s_waitcnt vmcnt(6)" ::: "memory");
        else if (rem == 2) asm volatile("s_waitcnt vmcnt(3)" ::: "memory");
        else if (rem == 1) asm volatile("s_waitcnt vmcnt(0)" ::: "memory");
        __builtin_amdgcn_s_barrier();
        asm volatile("s_waitcnt lgkmcnt(0)" ::: "memory");
        __builtin_amdgcn_sched_barrier(0);

        __builtin_amdgcn_s_setprio(1);
#pragma unroll
        for (int i = 0; i < 4; i++)
#pragma unroll
            for (int j = 0; j < 4; j++)
                acc[i][j] = __builtin_amdgcn_mfma_f32_16x16x32_bf16(afr[i], bfr[j], acc[i][j], 0, 0, 0);
        __builtin_amdgcn_s_setprio(0);
        __builtin_amdgcn_s_barrier();
        asm volatile("" ::: "memory");
    }

#pragma unroll
    for (int i = 0; i < 4; i++) {
        const int rowb = m0 + wm * 64 + i * 16 + q * 4;
#pragma unroll
        for (int j = 0; j < 4; j++) {
            const int col = n0 + wn * 64 + j * 16 + t;
#pragma unroll
            for (int r = 0; r < 4; r++) {
                const float v = acc[i][j][r];
                if constexpr (OUT == 0) {
                    ((__bf16*)Cg)[(size_t)(rowb + r) * ldc + col] = (__bf16)v;
                } else if constexpr (OUT == 1) {
                    float* C = (float*)Cg + (size_t)zi * sC;
                    C[(size_t)(rowb + r) * ldc + col] = v;
                } else {
                    atomicAdd(&((float*)Cg)[(size_t)(rowb + r) * ldc + col], v);
                }
            }
        }
    }
}

// fp32 -> bf16, 8 elems/thread, exact-size grid (n multiple of 2048).
__global__ __launch_bounds__(256) void cvt_bf16(
    const float* __restrict__ in, __bf16* __restrict__ out)
{
    const size_t i = ((size_t)blockIdx.x * 256 + threadIdx.x) * 8;
    float4 a = *(const float4*)(in + i);
    float4 b = *(const float4*)(in + i + 4);
    union { __bf16 h[8]; int4 v; } u;
    u.h[0]=(__bf16)a.x; u.h[1]=(__bf16)a.y; u.h[2]=(__bf16)a.z; u.h[3]=(__bf16)a.w;
    u.h[4]=(__bf16)b.x; u.h[5]=(__bf16)b.y; u.h[6]=(__bf16)b.z; u.h[7]=(__bf16)b.w;
    *(int4*)(out + i) = u.v;
}

// u[e] = sum_s x[s][e].  64 blocks x 64 rows; u pre-zeroed.
__global__ __launch_bounds__(256) void colsum_u(const float* __restrict__ x, float* __restrict__ u)
{
    const int c = threadIdx.x * 4;
    float4 a = {0.f,0.f,0.f,0.f};
    const int r0 = blockIdx.x * 64;
    for (int r = 0; r < 64; r++) {
        float4 v = *(const float4*)(x + (size_t)(r0 + r) * E_DIM + c);
        a.x += v.x; a.y += v.y; a.z += v.z; a.w += v.w;
    }
    atomicAdd(&u[c+0], a.x); atomicAdd(&u[c+1], a.y);
    atomicAdd(&u[c+2], a.z); atomicAdd(&u[c+3], a.w);
}

// kq[r] = Wk[r,:]·u ; qq[r] = Wq[r,:]·u  (r = h*E+j, 8192 rows each)
__global__ __launch_bounds__(256) void gemv_u(
    const float* __restrict__ Wk, const float* __restrict__ Wq,
    const float* __restrict__ u, float* __restrict__ kq, float* __restrict__ qq)
{
    const int gw = blockIdx.x * 4 + (threadIdx.x >> 6);
    const int lane = threadIdx.x & 63;
    const float* W = (gw < 8192) ? Wk + (size_t)gw * E_DIM
                                 : Wq + (size_t)(gw - 8192) * E_DIM;
    float s = 0.f;
#pragma unroll
    for (int i = 0; i < 4; i++) {
        float4 w = *(const float4*)(W + lane*16 + i*4);
        float4 z = *(const float4*)(u + lane*16 + i*4);
        s += w.x*z.x + w.y*z.y + w.z*z.z + w.w*z.w;
    }
#pragma unroll
    for (int o = 32; o > 0; o >>= 1) s += __shfl_down(s, o);
    if (lane == 0) { if (gw < 8192) kq[gw] = s; else qq[gw - 8192] = s; }
}

// zb[h*E+f] = sum_o bv[h][o] * A[h][o][f]; zb pre-zeroed. grid (4,8,4)
__global__ __launch_bounds__(256) void colsum_zb(
    const __bf16* __restrict__ Ab, const float* __restrict__ bv, float* __restrict__ zb)
{
    const int h = blockIdx.y;
    const int f = blockIdx.x * 256 + threadIdx.x;
    const int o0 = blockIdx.z * 256;
    const __bf16* A = Ab + (size_t)h * E_DIM * E_DIM + (size_t)o0 * E_DIM + f;
    const float* bvh = bv + h * E_DIM + o0;
    float s = 0.f;
    for (int o = 0; o < 256; o++) s += bvh[o] * (float)A[(size_t)o * E_DIM];
    atomicAdd(&zb[h * E_DIM + f], s);
}

// oc[g] = zb·Wz[g,:] + bz[g]   (K=8192, one wave per row)
__global__ __launch_bounds__(256) void gemv_oc(
    const float* __restrict__ Wz, const float* __restrict__ zb,
    const float* __restrict__ bz, float* __restrict__ oc)
{
    const int gw = blockIdx.x * 4 + (threadIdx.x >> 6);
    const int lane = threadIdx.x & 63;
    const float* W = Wz + (size_t)gw * (H_DIM * E_DIM);
    float s = 0.f;
#pragma unroll
    for (int i = 0; i < 32; i++) {
        float4 w = *(const float4*)(W + i*256 + lane*4);
        float4 z = *(const float4*)(zb + i*256 + lane*4);
        s += w.x*z.x + w.y*z.y + w.z*z.z + w.w*z.w;
    }
#pragma unroll
    for (int o = 32; o > 0; o >>= 1) s += __shfl_down(s, o);
    if (lane == 0) oc[gw] = s + bz[gw];
}

// softmax over f with fused rank-1 bias terms and 1/sqrt(E) scale.
__global__ __launch_bounds__(256) void softmax_fused(
    const float* __restrict__ Sc, const float* __restrict__ kq,
    const float* __restrict__ qq, const float* __restrict__ bk,
    const float* __restrict__ bq, __bf16* __restrict__ Aout)
{
    __shared__ float red[4];
    const int row = blockIdx.x;
    const int h = row >> 10;
    const int tid = threadIdx.x, lane = tid & 63, wave = tid >> 6;
    const float kqj = kq[row], bkj = bk[row];
    const float cst = (float)S_DIM * bkj;

    float4 v = ((const float4*)(Sc + (size_t)row * E_DIM))[tid];
    const int c = tid * 4;
    float4 qv = *(const float4*)(qq + (h << 10) + c);
    float4 bv = *(const float4*)(bq + (h << 10) + c);
    v.x = (v.x + kqj*bv.x + bkj*qv.x + cst*bv.x) * 0.03125f;
    v.y = (v.y + kqj*bv.y + bkj*qv.y + cst*bv.y) * 0.03125f;
    v.z = (v.z + kqj*bv.z + bkj*qv.z + cst*bv.z) * 0.03125f;
    v.w = (v.w + kqj*bv.w + bkj*qv.w + cst*bv.w) * 0.03125f;

    float m = fmaxf(fmaxf(v.x, v.y), fmaxf(v.z, v.w));
#pragma unroll
    for (int o = 32; o > 0; o >>= 1) m = fmaxf(m, __shfl_down(m, o));
    if (lane == 0) red[wave] = m;
    __syncthreads();
    m = fmaxf(fmaxf(red[0], red[1]), fmaxf(red[2], red[3]));
    __syncthreads();

    const float e0 = __expf(v.x - m), e1 = __expf(v.y - m);
    const float e2 = __expf(v.z - m), e3 = __expf(v.w - m);
    float s = e0 + e1 + e2 + e3;
#pragma unroll
    for (int o = 32; o > 0; o >>= 1) s += __shfl_down(s, o);
    if (lane == 0) red[wave] = s;
    __syncthreads();
    s = red[0] + red[1] + red[2] + red[3];
    const float inv = 1.f / s;

    __bf16* out = Aout + (size_t)row * E_DIM + c;
    out[0] = (__bf16)(e0*inv); out[1] = (__bf16)(e1*inv);
    out[2] = (__bf16)(e2*inv); out[3] = (__bf16)(e3*inv);
}

// LN + residual. X = sum of NPART fp32 partials (stride S*E) + optional
// per-column bias cb. out = LN(X)*g + b + resid.
template <int NPART, bool CB, bool WRITE_BF16>
__global__ __launch_bounds__(256) void ln_residual(
    const float* __restrict__ X, const float* __restrict__ cb,
    const float* __restrict__ resid,
    const float* __restrict__ g, const float* __restrict__ b,
    __bf16* __restrict__ outB, float* __restrict__ outF)
{
    __shared__ float redS[4], redQ[4];
    const int row = blockIdx.x;
    const int tid = threadIdx.x, lane = tid & 63, wave = tid >> 6;
    const size_t SE = (size_t)S_DIM * E_DIM;

    float4 v = ((const float4*)(X + (size_t)row * E_DIM))[tid];
#pragma unroll
    for (int p = 1; p < NPART; ++p) {
        float4 v1 = ((const float4*)(X + (size_t)p * SE + (size_t)row * E_DIM))[tid];
        v.x += v1.x; v.y += v1.y; v.z += v1.z; v.w += v1.w;
    }
    if constexpr (CB) {
        float4 cv = ((const float4*)cb)[tid];
        v.x += cv.x; v.y += cv.y; v.z += cv.z; v.w += cv.w;
    }
    float s = v.x + v.y + v.z + v.w;
    float q = v.x*v.x + v.y*v.y + v.z*v.z + v.w*v.w;
#pragma unroll
    for (int o = 32; o > 0; o >>= 1) { s += __shfl_down(s, o); q += __shfl_down(q, o); }
    if (lane == 0) { redS[wave] = s; redQ[wave] = q; }
    __syncthreads();
    s = redS[0]+redS[1]+redS[2]+redS[3];
    q = redQ[0]+redQ[1]+redQ[2]+redQ[3];

    const float mean = s * (1.f / E_DIM);
    const float var  = q * (1.f / E_DIM) - mean * mean;
    const float rstd = rsqrtf(var + 1e-5f);

    const int c0 = tid * 4;
    float4 rv = ((const float4*)(resid + (size_t)row * E_DIM))[tid];
    const float res[4] = {rv.x, rv.y, rv.z, rv.w};
    const float* vp = &v.x;
#pragma unroll
    for (int i = 0; i < 4; i++) {
        const float o = (vp[i] - mean) * rstd * g[c0+i] + b[c0+i] + res[i];
        outF[(size_t)row * E_DIM + c0 + i] = o;
        if constexpr (WRITE_BF16) outB[(size_t)row * E_DIM + c0 + i] = (__bf16)o;
    }
}

// ---------------------------------------------------------------------------
extern "C" void kernel_launch(void* const* d_in, const int* in_sizes, int n_in,
                              void* d_out, int out_size, void* d_ws, size_t ws_size,
                              hipStream_t stream)
{
    const float* x   = (const float*)d_in[0];
    const float* Wq  = (const float*)d_in[1];
    const float* bq  = (const float*)d_in[2];
    const float* Wk  = (const float*)d_in[3];
    const float* bk  = (const float*)d_in[4];
    const float* Wv  = (const float*)d_in[5];
    const float* bv  = (const float*)d_in[6];
    const float* Wz  = (const float*)d_in[7];
    const float* bz  = (const float*)d_in[8];
    const float* g1  = (const float*)d_in[9];
    const float* b1  = (const float*)d_in[10];
    const float* Wf  = (const float*)d_in[11];
    const float* bfp = (const float*)d_in[12];
    const float* g2  = (const float*)d_in[13];
    const float* b2  = (const float*)d_in[14];

    char* ws = (char*)d_ws;
    const long long EE = (long long)E_DIM * E_DIM;
    const long long SE = (long long)S_DIM * E_DIM;
    const size_t MB = 1024ull * 1024ull;

    // bf16 operand copies
    __bf16* xb   = (__bf16*)(ws);             //  8 MiB
    __bf16* Wqb  = (__bf16*)(ws +   8*MB);    // 16 MiB
    __bf16* Wkb  = (__bf16*)(ws +  24*MB);    // 16 MiB
    __bf16* Wvb  = (__bf16*)(ws +  40*MB);    // 16 MiB
    __bf16* Wzb  = (__bf16*)(ws +  56*MB);    // 16 MiB
    __bf16* Wfb  = (__bf16*)(ws +  72*MB);    //  2 MiB
    float*  Gf   = (float*) (ws +  74*MB);    //  4 MiB
    __bf16* Gb   = (__bf16*)(ws +  78*MB);    //  2 MiB
    float*  PTf  = (float*) (ws +  80*MB);    //  4 MiB
    __bf16* PTb  = (__bf16*)(ws +  84*MB);    //  2 MiB
    float*  u    = (float*) (ws +  86*MB);
    float*  kq   = (float*) (ws +  86*MB +  65536);
    float*  qq   = (float*) (ws +  86*MB + 131072);
    float*  zb   = (float*) (ws +  86*MB + 196608);
    float*  oc   = (float*) (ws +  86*MB + 262144);
    __bf16* LN1b = (__bf16*)(ws +  87*MB);    //  8 MiB
    float*  LN1f = (float*) (ws +  95*MB);    // 16 MiB
    __bf16* Tb   = (__bf16*)(ws + 111*MB);    // 16 MiB  (dead after scores)
    float*  Sc   = (float*) (ws + 127*MB);    // 32 MiB  (dead after softmax)
    __bf16* Ab   = (__bf16*)(ws + 159*MB);    // 16 MiB  (dead after Mcat/zb)
    __bf16* Mcat = (__bf16*)(ws + 175*MB);    // 16 MiB  (dead after PT; end 191)
    float*  Ob   = (float*) (ws + 111*MB);    // 32 MiB  2 partials (over Tb+Sc lo)
    float*  FNb  = (float*) (ws + 111*MB);    // 32 MiB  2 partials (Ob dead after LN1)

    dim3 blk(256);
    dim3 blk2(512);

    // zero accumulators (ws is 0xAA-poisoned)
    hipMemsetAsync(Gf,  0, 4*MB, stream);
    hipMemsetAsync(PTf, 0, 4*MB, stream);
    hipMemsetAsync(u,   0, E_DIM*4, stream);
    hipMemsetAsync(zb,  0, H_DIM*E_DIM*4, stream);

    // fp32 -> bf16 operand conversions
    cvt_bf16<<<dim3(2048), blk, 0, stream>>>(x,  xb);
    cvt_bf16<<<dim3(4096), blk, 0, stream>>>(Wq, Wqb);
    cvt_bf16<<<dim3(4096), blk, 0, stream>>>(Wk, Wkb);
    cvt_bf16<<<dim3(4096), blk, 0, stream>>>(Wv, Wvb);
    cvt_bf16<<<dim3(4096), blk, 0, stream>>>(Wz, Wzb);
    cvt_bf16<<<dim3(512),  blk, 0, stream>>>(Wf, Wfb);

    // u = colsum(x); kq = Wk u; qq = Wq u  (fp32 exact)
    colsum_u<<<dim3(64), blk, 0, stream>>>(x, u);
    gemv_u<<<dim3(4096), blk, 0, stream>>>(Wk, Wq, u, kq, qq);

    // G = x^T x  (TN both, split-K 8x512, atomic fp32) ; then bf16 copy
    gemm128<2, 2, 2><<<dim3(8, 8, 8), blk, 0, stream>>>(
        xb, xb, (void*)Gf, nullptr, 512, 512, E_DIM, E_DIM, E_DIM, 0, 0, 0, 1.f);
    cvt_bf16<<<dim3(512), blk, 0, stream>>>(Gf, Gb);

    // T = Wk_all G  (flat M=8192, shared B; G symmetric) -> bf16
    gemm256<0><<<dim3(8, 32, 1), blk2, 0, stream>>>(
        Wkb, Gb, (void*)Tb, E_DIM, 0, E_DIM, E_DIM, E_DIM, 0, 0);
    // scores_raw = T Wq_h^T  (flat M=8192, per-head B via m0>>10) -> fp32
    gemm256<1><<<dim3(8, 32, 1), blk2, 0, stream>>>(
        Tb, Wqb, (void*)Sc, E_DIM, 0, E_DIM, E_DIM, E_DIM, EE, 0);
    // A_h = softmax((raw + rank1)/32)
    softmax_fused<<<dim3(H_DIM * E_DIM), blk, 0, stream>>>(Sc, kq, qq, bk, bq, Ab);

    // Mcat[e][h*E+f] = (Wv_h^T A_h)[e][f]  (TN both)
    gemm128<2, 2, 0><<<dim3(8, 8, 8), blk, 0, stream>>>(
        Wvb, Ab, (void*)Mcat, nullptr, E_DIM, 0, E_DIM, E_DIM, H_DIM * E_DIM,
        EE, EE, E_DIM, 1.f);
    // zb = bv^T A ; oc = Wz zb + bz
    colsum_zb<<<dim3(4, 8, 4), blk, 0, stream>>>(Ab, bv, zb);
    gemv_oc<<<dim3(256), blk, 0, stream>>>(Wz, zb, bz, oc);

    // PT[g][e] = sum_F Wz[g][F] Mcat[e][F]  (split-K 8x1024, atomic fp32)
    gemm256<2><<<dim3(8, 4, 8), blk2, 0, stream>>>(
        Wzb, Mcat, (void*)PTf, 1024, 1024, H_DIM * E_DIM, H_DIM * E_DIM,
        E_DIM, 0, 0);
    cvt_bf16<<<dim3(512), blk, 0, stream>>>(PTf, PTb);

    // O partials = x PT^T  (split-K 2x512 -> 2 fp32 partials; bias oc in LN)
    gemm256<1><<<dim3(8, 16, 2), blk2, 0, stream>>>(
        xb, PTb, (void*)Ob, 512, 512, E_DIM, E_DIM, E_DIM, 0, SE);
    // LN1 = LN(O0+O1+oc)*g1+b1 + x
    ln_residual<2, true, true><<<dim3(S_DIM), blk, 0, stream>>>(
        Ob, oc, x, g1, b1, LN1b, LN1f);

    // FN partials = LN1 Wf^T  (split-K 2x512; bias bf in LN)
    gemm256<1><<<dim3(8, 16, 2), blk2, 0, stream>>>(
        LN1b, Wfb, (void*)FNb, 512, 512, E_DIM, E_DIM, E_DIM, 0, SE);
    // out = LN(FN0+FN1+bf)*g2+b2 + LN1
    ln_residual<2, true, false><<<dim3(S_DIM), blk, 0, stream>>>(
        FNb, bfp, LN1f, g2, b2, nullptr, (float*)d_out);
}